// Round 1
// baseline (446.645 us; speedup 1.0000x reference)
//
#include <hip/hip_runtime.h>

// Local 3x3 variance (zero-padded, stride 1, divisor 9) over (8,32,512,512) fp32.
// out = boxsum(x^2)/9 - (boxsum(x)/9)^2
//
// Layout: one wave (64 lanes) per 256-wide x 64-tall tile of one (b,c) plane.
// Lane handles 4 consecutive columns (float4). Column halo via __shfl from
// neighbor lanes; strip-edge lanes load one scalar. 3-row rolling register
// window of row-sums (x and x^2). Zero padding = zero contributions, /9 fixed.

#define IMG_H 512
#define IMG_W 512

__global__ __launch_bounds__(64) void var3x3_kernel(const float* __restrict__ x,
                                                    float* __restrict__ out) {
    const int lane  = threadIdx.x;      // 0..63
    const int ws    = blockIdx.x;       // 0..1   (256-wide strips)
    const int hc    = blockIdx.y;       // 0..7   (64-row chunks)
    const int plane = blockIdx.z;       // 0..255 (b*c)

    const float* px = x   + (size_t)plane * (IMG_H * IMG_W);
    float*       po = out + (size_t)plane * (IMG_H * IMG_W);

    const int w0 = ws * 256 + lane * 4; // first of this lane's 4 columns
    const int r0 = hc * 64;             // first output row of this chunk

    float4 rsA = make_float4(0.f, 0.f, 0.f, 0.f);  // row-sums of x, row h-2
    float4 rsB = make_float4(0.f, 0.f, 0.f, 0.f);  // row h-1
    float4 rqA = make_float4(0.f, 0.f, 0.f, 0.f);  // row-sums of x^2
    float4 rqB = make_float4(0.f, 0.f, 0.f, 0.f);

    const float inv9 = 1.0f / 9.0f;

    // iterate input rows r0-1 .. r0+64 (66 rows); emit output rows r0..r0+63
    for (int i = 0; i < 66; ++i) {
        const int h = r0 - 1 + i;       // wave-uniform
        float4 v = make_float4(0.f, 0.f, 0.f, 0.f);
        float lval = 0.f, rval = 0.f;
        if (h >= 0 && h < IMG_H) {      // uniform branch: all lanes same h
            v = *reinterpret_cast<const float4*>(px + (size_t)h * IMG_W + w0);
            if (lane == 0 && w0 > 0)
                lval = px[(size_t)h * IMG_W + w0 - 1];
            if (lane == 63 && (w0 + 4) < IMG_W)
                rval = px[(size_t)h * IMG_W + w0 + 4];
        }
        // column halo from neighbor lanes (all 64 lanes active here)
        const float fromUp = __shfl_up(v.w, 1);   // lane-1's last element
        const float fromDn = __shfl_down(v.x, 1); // lane+1's first element
        const float left  = (lane == 0)  ? lval : fromUp;
        const float right = (lane == 63) ? rval : fromDn;

        // 3-wide horizontal sums for this row
        float4 rsC, rqC;
        rsC.x = left + v.x + v.y;
        rsC.y = v.x  + v.y + v.z;
        rsC.z = v.y  + v.z + v.w;
        rsC.w = v.z  + v.w + right;
        const float l2 = left * left, a2 = v.x * v.x, b2 = v.y * v.y;
        const float c2 = v.z * v.z,  d2 = v.w * v.w, r2 = right * right;
        rqC.x = l2 + a2 + b2;
        rqC.y = a2 + b2 + c2;
        rqC.z = b2 + c2 + d2;
        rqC.w = c2 + d2 + r2;

        if (i >= 2) {
            const int ho = h - 1;       // output row r0 + (i-2)
            float4 o;
            {
                const float s = rsA.x + rsB.x + rsC.x;
                const float q = rqA.x + rqB.x + rqC.x;
                const float m = s * inv9;
                o.x = q * inv9 - m * m;
            }
            {
                const float s = rsA.y + rsB.y + rsC.y;
                const float q = rqA.y + rqB.y + rqC.y;
                const float m = s * inv9;
                o.y = q * inv9 - m * m;
            }
            {
                const float s = rsA.z + rsB.z + rsC.z;
                const float q = rqA.z + rqB.z + rqC.z;
                const float m = s * inv9;
                o.z = q * inv9 - m * m;
            }
            {
                const float s = rsA.w + rsB.w + rsC.w;
                const float q = rqA.w + rqB.w + rqC.w;
                const float m = s * inv9;
                o.w = q * inv9 - m * m;
            }
            *reinterpret_cast<float4*>(po + (size_t)ho * IMG_W + w0) = o;
        }
        rsA = rsB; rsB = rsC;
        rqA = rqB; rqB = rqC;
    }
}

extern "C" void kernel_launch(void* const* d_in, const int* in_sizes, int n_in,
                              void* d_out, int out_size, void* d_ws, size_t ws_size,
                              hipStream_t stream) {
    const float* x = (const float*)d_in[0];
    float* out = (float*)d_out;
    dim3 grid(2, 8, 256);   // w-strips, h-chunks, planes (8*32)
    dim3 block(64);
    var3x3_kernel<<<grid, block, 0, stream>>>(x, out);
}

// Round 3
// 440.034 us; speedup vs baseline: 1.0150x; 1.0150x over previous
//
#include <hip/hip_runtime.h>

// Local 3x3 variance (zero-padded, stride 1, divisor 9) over (8,32,512,512) fp32.
// out = boxsum(x^2)/9 - (boxsum(x)/9)^2
//
// One wave (64 lanes) handles a 256-col x 16-row tile; 4 waves per 256-thread
// block (independent row tiles). Lane owns 4 consecutive columns (float4).
// Column halo via __shfl; strip-edge lanes load one scalar. Rows are loaded
// with clamped addresses + 0/1 mask (zero padding), depth-1 software prefetch
// so each row's load is in flight during the previous row's compute.

#define IMG_H 512
#define IMG_W 512
#define TH 16   // output rows per wave

typedef float vfloat4 __attribute__((ext_vector_type(4)));  // native vec for nontemporal store

__global__ __launch_bounds__(256, 6) void var3x3_kernel(const float* __restrict__ x,
                                                        float* __restrict__ out) {
    const int tid   = threadIdx.x;
    const int lane  = tid & 63;
    const int wavei = tid >> 6;         // 0..3
    const int ws    = blockIdx.x;       // 0..1   (256-wide strips)
    const int hc    = blockIdx.y;       // 0..7   (64-row chunks)
    const int plane = blockIdx.z;       // 0..255 (b*c)

    const float* __restrict__ px = x   + (size_t)plane * (IMG_H * IMG_W);
    float*       __restrict__ po = out + (size_t)plane * (IMG_H * IMG_W);

    const int w0 = ws * 256 + lane * 4;     // first of this lane's 4 columns
    const int r0 = hc * 64 + wavei * TH;    // first output row of this wave

    const bool haveL = (w0 > 0);            // lane 0 of strip 1 needs scalar halo
    const bool haveR = (w0 + 4 < IMG_W);    // lane 63 of strip 0 needs scalar halo
    const float inv9 = 1.0f / 9.0f;

    float4 rsA = {0,0,0,0}, rsB = {0,0,0,0};   // rolling row-sums of x
    float4 rqA = {0,0,0,0}, rqB = {0,0,0,0};   // rolling row-sums of x^2

    // input row i -> h = r0-1+i, i = 0..TH+1 (18 rows)
    // clamped pointer + 0/1 validity mask implements zero padding
    auto rowbase = [&](int i) -> const float* {
        int h = r0 - 1 + i;
        h = h < 0 ? 0 : (h > IMG_H - 1 ? IMG_H - 1 : h);
        return px + (size_t)h * IMG_W;
    };
    auto rowmask = [&](int i) -> float {
        int h = r0 - 1 + i;
        return (h >= 0 && h < IMG_H) ? 1.0f : 0.0f;
    };

    // prefetch row 0
    const float* p0 = rowbase(0);
    float4 vn = *reinterpret_cast<const float4*>(p0 + w0);
    float lnv = 0.f, rnv = 0.f;
    if (lane == 0 && haveL)  lnv = p0[w0 - 1];
    if (lane == 63 && haveR) rnv = p0[w0 + 4];
    float mn = rowmask(0);

    #pragma unroll 3
    for (int i = 0; i < TH + 2; ++i) {
        float4 v = vn;
        float  lv = lnv, rv = rnv, m = mn;

        if (i < TH + 1) {   // wave-uniform; prefetch next row
            const float* p = rowbase(i + 1);
            vn = *reinterpret_cast<const float4*>(p + w0);
            lnv = 0.f; rnv = 0.f;
            if (lane == 0 && haveL)  lnv = p[w0 - 1];
            if (lane == 63 && haveR) rnv = p[w0 + 4];
            mn = rowmask(i + 1);
        }

        // zero-padding mask
        v.x *= m; v.y *= m; v.z *= m; v.w *= m; lv *= m; rv *= m;

        // column halo from neighbor lanes
        const float fu = __shfl_up(v.w, 1);
        const float fd = __shfl_down(v.x, 1);
        const float left  = (lane == 0)  ? lv : fu;
        const float right = (lane == 63) ? rv : fd;

        // 3-wide horizontal sums for this row
        float4 rsC, rqC;
        rsC.x = left + v.x + v.y;
        rsC.y = v.x  + v.y + v.z;
        rsC.z = v.y  + v.z + v.w;
        rsC.w = v.z  + v.w + right;
        const float l2 = left*left, a2 = v.x*v.x, b2 = v.y*v.y;
        const float c2 = v.z*v.z,  d2 = v.w*v.w, r2 = right*right;
        rqC.x = l2 + a2 + b2;
        rqC.y = a2 + b2 + c2;
        rqC.z = b2 + c2 + d2;
        rqC.w = c2 + d2 + r2;

        if (i >= 2) {
            const int ho = r0 + i - 2;
            vfloat4 o;
            { const float s = rsA.x+rsB.x+rsC.x, q = rqA.x+rqB.x+rqC.x, mm = s*inv9; o.x = q*inv9 - mm*mm; }
            { const float s = rsA.y+rsB.y+rsC.y, q = rqA.y+rqB.y+rqC.y, mm = s*inv9; o.y = q*inv9 - mm*mm; }
            { const float s = rsA.z+rsB.z+rsC.z, q = rqA.z+rqB.z+rqC.z, mm = s*inv9; o.z = q*inv9 - mm*mm; }
            { const float s = rsA.w+rsB.w+rsC.w, q = rqA.w+rqB.w+rqC.w, mm = s*inv9; o.w = q*inv9 - mm*mm; }
            __builtin_nontemporal_store(o, reinterpret_cast<vfloat4*>(po + (size_t)ho * IMG_W + w0));
        }
        rsA = rsB; rsB = rsC;
        rqA = rqB; rqB = rqC;
    }
}

extern "C" void kernel_launch(void* const* d_in, const int* in_sizes, int n_in,
                              void* d_out, int out_size, void* d_ws, size_t ws_size,
                              hipStream_t stream) {
    const float* x = (const float*)d_in[0];
    float* out = (float*)d_out;
    dim3 grid(2, 8, 256);   // w-strips, 64-row chunks, planes (8*32)
    dim3 block(256);        // 4 independent waves, each a 256x16 tile
    var3x3_kernel<<<grid, block, 0, stream>>>(x, out);
}